// Round 4
// baseline (44.870 us; speedup 1.0000x reference)
//
#include <hip/hip_runtime.h>

#define NTRAIN 200000
#define NB     256
#define BIT    64
#define MAXS   30
#define NCLS   100
#define ESPL   8            // entry-chunks per class
#define EPB    4            // pool entries per block
#define CHUNK  4096
#define PERT   16
#define NREG   16           // regularizer blocks
#define NCLSB  (NCLS * ESPL)        // 800
#define GRID_N (NCLSB + NREG)       // 816
#define MVAL   128.0f
#define ALPHA  0.01f

// Single fused kernel. Blocks [0,800): (class c = j>>3, entry-chunk e = j&7).
// Blocks [800,816): regularizer partials. Last block to finish reduces all
// partials and writes the scalar loss.
__global__ __launch_bounds__(256, 4) void dsh_fused_kernel(
    const float* __restrict__ u, const int* __restrict__ y,
    const int* __restrict__ ind, const float* __restrict__ U,
    const float* __restrict__ Y,
    float* __restrict__ partial, int* __restrict__ cntw,
    int* __restrict__ counter, float* __restrict__ out)
{
    __shared__ int   y_l[NB];
    __shared__ int   ind_l[NB];
    __shared__ int   addl[NB];      // bank indices whose Yeff flips to c
    __shared__ int   reml[NB];      // bank indices whose Yeff flips away from c
    __shared__ float up_l[EPB * BIT];
    __shared__ int   pool[MAXS];
    __shared__ int   povr[EPB];
    __shared__ int   wsA[4], wsB[4], wsC[4];
    __shared__ float redf[4], redg[4];
    __shared__ int   redi[4];
    __shared__ int   lastflag;

    const int t    = threadIdx.x;
    const int j    = blockIdx.x;
    const int lane = t & 63;
    const int wave = t >> 6;

    float myPartial = 0.f;          // meaningful on t==0
    int   myCntW    = -1;

    if (j >= NCLSB) {
        // ---- regularizer partial: 1024 u-elements per block ----
        const int q = j - NCLSB;
        float4 v = ((const float4*)u)[q * 256 + t];
        float a = fabsf(fabsf(v.x) - 1.f) + fabsf(fabsf(v.y) - 1.f)
                + fabsf(fabsf(v.z) - 1.f) + fabsf(fabsf(v.w) - 1.f);
        #pragma unroll
        for (int off = 32; off; off >>= 1) a += __shfl_down(a, off, 64);
        if (lane == 0) redf[wave] = a;
        __syncthreads();
        myPartial = redf[0] + redf[1] + redf[2] + redf[3];
    } else {
        const int c = j >> 3;
        const int e = j & 7;
        const float cf = (float)c;

        const int myi = ind[t];
        const int myy = y[t];
        ind_l[t] = myi;
        y_l[t]   = myy;
        const float ybank = Y[myi];         // bank label at my scatter target

        // ---- batch multiplicity + scatter-correction lists (one barrier) ----
        const bool ismem = (myy == c);
        const bool fneg  = ismem && (ybank != cf);   // becomes class c
        const bool fpos  = (!ismem) && (ybank == cf);// stops being class c
        unsigned long long balm = __ballot(ismem);
        unsigned long long bala = __ballot(fneg);
        unsigned long long balr = __ballot(fpos);
        if (lane == 0) {
            wsA[wave] = (int)__popcll(balm);
            wsB[wave] = (int)__popcll(bala);
            wsC[wave] = (int)__popcll(balr);
        }
        __syncthreads();
        const int mult = wsA[0] + wsA[1] + wsA[2] + wsA[3];
        const int nadd = wsB[0] + wsB[1] + wsB[2] + wsB[3];
        const int nrem = wsC[0] + wsC[1] + wsC[2] + wsC[3];

        if (mult > 0) {
            int pa = 0, pr = 0;
            #pragma unroll
            for (int w = 0; w < 4; ++w) if (w < wave) { pa += wsB[w]; pr += wsC[w]; }
            const unsigned long long lm = (1ull << lane) - 1ull;
            if (fneg) addl[pa + (int)__popcll(bala & lm)] = myi;
            if (fpos) reml[pr + (int)__popcll(balr & lm)] = myi;
            __syncthreads();                // lists ready; wsA reusable

            // ---- scan: first MAXS ascending matches of Yeff == c ----
            int count = 0;
            for (int base = 0; base < NTRAIN && count < MAXS; base += CHUNK) {
                const int s = base + t * PERT;
                unsigned mbits = 0;
                int mcnt = 0;
                if (s < NTRAIN) {           // NTRAIN % PERT == 0: full vectors
                    const float4* yp = (const float4*)(Y + s);
                    #pragma unroll
                    for (int q2 = 0; q2 < 4; ++q2) {
                        float4 v = yp[q2];
                        if (v.x == cf) mbits |= 1u << (q2 * 4 + 0);
                        if (v.y == cf) mbits |= 1u << (q2 * 4 + 1);
                        if (v.z == cf) mbits |= 1u << (q2 * 4 + 2);
                        if (v.w == cf) mbits |= 1u << (q2 * 4 + 3);
                    }
                    for (int a2 = 0; a2 < nadd; ++a2) {        // ~2 broadcast reads
                        unsigned rel = (unsigned)(addl[a2] - s);
                        if (rel < (unsigned)PERT) mbits |= 1u << rel;
                    }
                    for (int r2 = 0; r2 < nrem; ++r2) {        // ~5 broadcast reads
                        unsigned rel = (unsigned)(reml[r2] - s);
                        if (rel < (unsigned)PERT) mbits &= ~(1u << rel);
                    }
                    mcnt = __popc(mbits);
                }
                // ordered inclusive block scan of mcnt
                int x = mcnt;
                #pragma unroll
                for (int off = 1; off < 64; off <<= 1) {
                    int v2 = __shfl_up(x, off, 64);
                    if (lane >= off) x += v2;
                }
                if (lane == 63) wsA[wave] = x;
                __syncthreads();
                int r = count + (x - mcnt);
                #pragma unroll
                for (int w = 0; w < 4; ++w) if (w < wave) r += wsA[w];
                #pragma unroll
                for (int k = 0; k < PERT; ++k) {
                    if ((mbits >> k) & 1u) {
                        if (r < MAXS) pool[r] = s + k;
                        ++r;
                    }
                }
                count += wsA[0] + wsA[1] + wsA[2] + wsA[3];
                __syncthreads();
            }
            const int cnt = (count < MAXS) ? count : MAXS;

            // ---- prefetch my u-row (latency hides under U gather below) ----
            float4 ur[16];
            {
                const float4* urp = (const float4*)(u + t * BIT);
                #pragma unroll
                for (int q2 = 0; q2 < 16; ++q2) ur[q2] = urp[q2];
            }

            // ---- overrides among this block's pool entries + gather ----
            const int p0 = e * EPB;
            const int pe = (p0 + EPB < cnt) ? p0 + EPB : cnt;
            if (t < EPB) povr[t] = -1;
            __syncthreads();
            for (int k2 = p0; k2 < pe; ++k2)
                if (myi == pool[k2]) povr[k2 - p0] = t;   // at most one t
            __syncthreads();
            {
                const int pp = t >> 6;
                const int d  = t & 63;
                float v = 0.f;
                if (p0 + pp < pe) {
                    const int ov = povr[pp];
                    v = (ov >= 0) ? u[ov * BIT + d] : U[pool[p0 + pp] * BIT + d];
                }
                up_l[t] = v;
            }
            __syncthreads();

            // ---- pair loss: thread t = batch row t vs entries [p0, pe) ----
            const bool same = (myy == c);
            const int npool = pe - p0;
            float acc = 0.f;
            for (int pp = 0; pp < npool; ++pp) {
                const float4* up = (const float4*)(up_l + pp * BIT);
                float d0 = 0.f, d1 = 0.f, d2 = 0.f, d3 = 0.f;
                #pragma unroll
                for (int q2 = 0; q2 < 16; ++q2) {
                    float4 v = up[q2];
                    float a0 = ur[q2].x - v.x; d0 += a0 * a0;
                    float a1 = ur[q2].y - v.y; d1 += a1 * a1;
                    float a2 = ur[q2].z - v.z; d2 += a2 * a2;
                    float a3 = ur[q2].w - v.w; d3 += a3 * a3;
                }
                const float dist = (d0 + d1) + (d2 + d3);
                acc += same ? dist : fmaxf(MVAL - dist, 0.f);
            }
            #pragma unroll
            for (int off = 32; off; off >>= 1) acc += __shfl_down(acc, off, 64);
            if (lane == 0) redf[wave] = acc;
            __syncthreads();
            myPartial = (float)mult * (redf[0] + redf[1] + redf[2] + redf[3]);
            if (e == 0) myCntW = mult * cnt;
        } else {
            myPartial = 0.f;
            if (e == 0) myCntW = 0;
        }
    }

    // ---- epilogue: publish partial; last block reduces everything ----
    if (t == 0) {
        partial[j] = myPartial;
        if (myCntW >= 0) cntw[j >> 3] = myCntW;
        __threadfence();
        int old = __hip_atomic_fetch_add(counter, 1, __ATOMIC_ACQ_REL,
                                         __HIP_MEMORY_SCOPE_AGENT);
        lastflag = (old == GRID_N - 1);
    }
    __syncthreads();
    if (!lastflag) return;

    float p = 0.f, a = 0.f;
    #pragma unroll
    for (int k = 0; k < 4; ++k) {
        const int idx = t + 256 * k;
        if (idx < NCLSB)       p += partial[idx];
        else if (idx < GRID_N) a += partial[idx];
    }
    int cc = (t < NCLS) ? cntw[t] : 0;
    #pragma unroll
    for (int off = 32; off; off >>= 1) {
        p  += __shfl_down(p,  off, 64);
        a  += __shfl_down(a,  off, 64);
        cc += __shfl_down(cc, off, 64);
    }
    if (lane == 0) { redf[wave] = p; redg[wave] = a; redi[wave] = cc; }
    __syncthreads();
    if (t == 0) {
        const float P = redf[0] + redf[1] + redf[2] + redf[3];
        const float A = redg[0] + redg[1] + redg[2] + redg[3];
        const int   S = redi[0] + redi[1] + redi[2] + redi[3];
        out[0] = 0.5f * P / (256.0f * (float)S) + ALPHA * (A * (1.0f / 16384.0f));
    }
}

extern "C" void kernel_launch(void* const* d_in, const int* in_sizes, int n_in,
                              void* d_out, int out_size, void* d_ws, size_t ws_size,
                              hipStream_t stream) {
    const float* u   = (const float*)d_in[0];
    const int*   y   = (const int*)d_in[1];
    const int*   ind = (const int*)d_in[2];
    const float* U   = (const float*)d_in[3];
    const float* Y   = (const float*)d_in[4];
    float* out = (float*)d_out;

    float* partial = (float*)d_ws;                        // [816]
    int*   cntw    = (int*)((char*)d_ws + 4096);          // [100]
    int*   counter = (int*)((char*)d_ws + 8192);          // [1]

    hipMemsetAsync(counter, 0, sizeof(int), stream);      // reset arrival counter
    dsh_fused_kernel<<<dim3(GRID_N), dim3(256), 0, stream>>>(
        u, y, ind, U, Y, partial, cntw, counter, out);
}

// Round 5
// 41.610 us; speedup vs baseline: 1.0784x; 1.0784x over previous
//
#include <hip/hip_runtime.h>

#define NTRAIN 200000
#define NB     256
#define BIT    64
#define MAXS   30
#define NCLS   100
#define ESPL   8            // entry-chunks per class
#define EPB    4            // pool entries per block
#define CHUNK  4096
#define PERT   16
#define NREG   16           // regularizer blocks
#define NCLSB  (NCLS * ESPL)        // 800
#define GRID_N (NCLSB + NREG)       // 816
#define MVAL   128.0f
#define ALPHA  0.01f

// Single fused kernel, atomic-only cross-block communication (no fences).
// Blocks [0,800): (class c = j>>3, entry-chunk e = j&7).
// Blocks [800,816): regularizer partials. Last arrival computes the loss.
__global__ __launch_bounds__(256, 4) void dsh_fused_kernel(
    const float* __restrict__ u, const int* __restrict__ y,
    const int* __restrict__ ind, const float* __restrict__ U,
    const float* __restrict__ Y,
    float* __restrict__ accf,   // [0]=pair sum, [1]=reg sum
    int* __restrict__ acci,     // [0]=sum mult*cnt, [1]=arrival counter
    float* __restrict__ out)
{
    __shared__ int   addl[NB];      // bank indices whose Yeff flips to c
    __shared__ int   reml[NB];      // bank indices whose Yeff flips away from c
    __shared__ float up_l[EPB * BIT];
    __shared__ int   pool[MAXS];
    __shared__ int   povr[EPB];
    __shared__ int   wsA[4], wsB[4], wsC[4];
    __shared__ float redf[4];

    const int t    = threadIdx.x;
    const int j    = blockIdx.x;
    const int lane = t & 63;
    const int wave = t >> 6;

    float myPair = 0.f;             // t==0: this block's contribution
    int   myCnt  = -1;
    const bool isReg = (j >= NCLSB);

    if (isReg) {
        // ---- regularizer partial: 1024 u-elements per block ----
        const int q = j - NCLSB;
        float4 v = ((const float4*)u)[q * 256 + t];
        float a = fabsf(fabsf(v.x) - 1.f) + fabsf(fabsf(v.y) - 1.f)
                + fabsf(fabsf(v.z) - 1.f) + fabsf(fabsf(v.w) - 1.f);
        #pragma unroll
        for (int off = 32; off; off >>= 1) a += __shfl_down(a, off, 64);
        if (lane == 0) redf[wave] = a;
        __syncthreads();
        myPair = redf[0] + redf[1] + redf[2] + redf[3];
    } else {
        const int c = j >> 3;
        const int e = j & 7;
        const float cf = (float)c;

        // ---- issue all front-end loads up front (one vmcnt wall) ----
        const int myi = ind[t];
        const int myy = y[t];
        const int s0  = t * PERT;
        float4 yv0, yv1, yv2, yv3;      // Y chunk 0, prefetched
        {
            const float4* yp = (const float4*)(Y + s0);
            yv0 = yp[0]; yv1 = yp[1]; yv2 = yp[2]; yv3 = yp[3];
        }
        const float ybank = Y[myi];     // dependent gather, overlaps yv loads

        // ---- ballots: multiplicity + scatter-correction lists ----
        const bool ismem = (myy == c);
        const bool fneg  = ismem && (ybank != cf);    // becomes class c
        const bool fpos  = (!ismem) && (ybank == cf); // stops being class c
        unsigned long long balm = __ballot(ismem);
        unsigned long long bala = __ballot(fneg);
        unsigned long long balr = __ballot(fpos);
        if (lane == 0) {
            wsA[wave] = (int)__popcll(balm);
            wsB[wave] = (int)__popcll(bala);
            wsC[wave] = (int)__popcll(balr);
        }
        __syncthreads();
        const int mult = wsA[0] + wsA[1] + wsA[2] + wsA[3];

        if (mult > 0) {
            const int nadd = wsB[0] + wsB[1] + wsB[2] + wsB[3];
            const int nrem = wsC[0] + wsC[1] + wsC[2] + wsC[3];
            int pa = 0, pr = 0;
            #pragma unroll
            for (int w = 0; w < 4; ++w) if (w < wave) { pa += wsB[w]; pr += wsC[w]; }
            const unsigned long long lm = (1ull << lane) - 1ull;
            if (fneg) addl[pa + (int)__popcll(bala & lm)] = myi;
            if (fpos) reml[pr + (int)__popcll(balr & lm)] = myi;
            __syncthreads();            // lists ready; wsA reusable

            // ---- scan chunk 0 (prefetched Y values) ----
            unsigned mbits = 0;
            if (yv0.x == cf) mbits |= 1u << 0;
            if (yv0.y == cf) mbits |= 1u << 1;
            if (yv0.z == cf) mbits |= 1u << 2;
            if (yv0.w == cf) mbits |= 1u << 3;
            if (yv1.x == cf) mbits |= 1u << 4;
            if (yv1.y == cf) mbits |= 1u << 5;
            if (yv1.z == cf) mbits |= 1u << 6;
            if (yv1.w == cf) mbits |= 1u << 7;
            if (yv2.x == cf) mbits |= 1u << 8;
            if (yv2.y == cf) mbits |= 1u << 9;
            if (yv2.z == cf) mbits |= 1u << 10;
            if (yv2.w == cf) mbits |= 1u << 11;
            if (yv3.x == cf) mbits |= 1u << 12;
            if (yv3.y == cf) mbits |= 1u << 13;
            if (yv3.z == cf) mbits |= 1u << 14;
            if (yv3.w == cf) mbits |= 1u << 15;
            for (int a2 = 0; a2 < nadd; ++a2) {
                unsigned rel = (unsigned)(addl[a2] - s0);
                if (rel < (unsigned)PERT) mbits |= 1u << rel;
            }
            for (int r2 = 0; r2 < nrem; ++r2) {
                unsigned rel = (unsigned)(reml[r2] - s0);
                if (rel < (unsigned)PERT) mbits &= ~(1u << rel);
            }
            const int mcnt = __popc(mbits);

            int x = mcnt;               // ordered inclusive wave scan
            #pragma unroll
            for (int off = 1; off < 64; off <<= 1) {
                int v2 = __shfl_up(x, off, 64);
                if (lane >= off) x += v2;
            }
            if (lane == 63) wsA[wave] = x;
            if (t < EPB) povr[t] = -1;  // piggyback before the barrier
            __syncthreads();
            int r = x - mcnt;
            #pragma unroll
            for (int w = 0; w < 4; ++w) if (w < wave) r += wsA[w];
            #pragma unroll
            for (int k = 0; k < PERT; ++k) {
                if ((mbits >> k) & 1u) {
                    if (r < MAXS) pool[r] = s0 + k;
                    ++r;
                }
            }
            int count = wsA[0] + wsA[1] + wsA[2] + wsA[3];
            __syncthreads();            // pool settled; wsA free

            // ---- cold continuation (~3-4% of classes) ----
            for (int base = CHUNK; base < NTRAIN && count < MAXS; base += CHUNK) {
                const int s = base + t * PERT;
                unsigned mb = 0;
                int mc = 0;
                if (s < NTRAIN) {       // NTRAIN % PERT == 0: full vectors
                    const float4* yp = (const float4*)(Y + s);
                    float4 a0 = yp[0], a1 = yp[1], a2v = yp[2], a3 = yp[3];
                    if (a0.x == cf) mb |= 1u << 0;
                    if (a0.y == cf) mb |= 1u << 1;
                    if (a0.z == cf) mb |= 1u << 2;
                    if (a0.w == cf) mb |= 1u << 3;
                    if (a1.x == cf) mb |= 1u << 4;
                    if (a1.y == cf) mb |= 1u << 5;
                    if (a1.z == cf) mb |= 1u << 6;
                    if (a1.w == cf) mb |= 1u << 7;
                    if (a2v.x == cf) mb |= 1u << 8;
                    if (a2v.y == cf) mb |= 1u << 9;
                    if (a2v.z == cf) mb |= 1u << 10;
                    if (a2v.w == cf) mb |= 1u << 11;
                    if (a3.x == cf) mb |= 1u << 12;
                    if (a3.y == cf) mb |= 1u << 13;
                    if (a3.z == cf) mb |= 1u << 14;
                    if (a3.w == cf) mb |= 1u << 15;
                    for (int a2 = 0; a2 < nadd; ++a2) {
                        unsigned rel = (unsigned)(addl[a2] - s);
                        if (rel < (unsigned)PERT) mb |= 1u << rel;
                    }
                    for (int r2 = 0; r2 < nrem; ++r2) {
                        unsigned rel = (unsigned)(reml[r2] - s);
                        if (rel < (unsigned)PERT) mb &= ~(1u << rel);
                    }
                    mc = __popc(mb);
                }
                int xx = mc;
                #pragma unroll
                for (int off = 1; off < 64; off <<= 1) {
                    int v2 = __shfl_up(xx, off, 64);
                    if (lane >= off) xx += v2;
                }
                if (lane == 63) wsA[wave] = xx;
                __syncthreads();
                int rr = count + (xx - mc);
                #pragma unroll
                for (int w = 0; w < 4; ++w) if (w < wave) rr += wsA[w];
                #pragma unroll
                for (int k = 0; k < PERT; ++k) {
                    if ((mb >> k) & 1u) {
                        if (rr < MAXS) pool[rr] = s + k;
                        ++rr;
                    }
                }
                count += wsA[0] + wsA[1] + wsA[2] + wsA[3];
                __syncthreads();
            }
            const int cnt = (count < MAXS) ? count : MAXS;

            // ---- prefetch my u-row (hides under the U pool gather) ----
            float4 ur[16];
            {
                const float4* urp = (const float4*)(u + t * BIT);
                #pragma unroll
                for (int q2 = 0; q2 < 16; ++q2) ur[q2] = urp[q2];
            }

            // ---- overrides among this block's pool entries + gather ----
            const int p0 = e * EPB;
            const int pe = (p0 + EPB < cnt) ? p0 + EPB : cnt;
            for (int k2 = p0; k2 < pe; ++k2)
                if (myi == pool[k2]) povr[k2 - p0] = t;   // at most one t
            __syncthreads();
            {
                const int pp = t >> 6;
                const int d  = t & 63;
                float v = 0.f;
                if (p0 + pp < pe) {
                    const int ov = povr[pp];
                    v = (ov >= 0) ? u[ov * BIT + d] : U[pool[p0 + pp] * BIT + d];
                }
                up_l[t] = v;
            }
            __syncthreads();

            // ---- pair loss: thread t = batch row t vs entries [p0, pe) ----
            const bool same = (myy == c);
            const int npool = pe - p0;
            float acc = 0.f;
            for (int pp = 0; pp < npool; ++pp) {
                const float4* up = (const float4*)(up_l + pp * BIT);
                float d0 = 0.f, d1 = 0.f, d2 = 0.f, d3 = 0.f;
                #pragma unroll
                for (int q2 = 0; q2 < 16; ++q2) {
                    float4 v = up[q2];
                    float a0 = ur[q2].x - v.x; d0 += a0 * a0;
                    float a1 = ur[q2].y - v.y; d1 += a1 * a1;
                    float a2 = ur[q2].z - v.z; d2 += a2 * a2;
                    float a3 = ur[q2].w - v.w; d3 += a3 * a3;
                }
                const float dist = (d0 + d1) + (d2 + d3);
                acc += same ? dist : fmaxf(MVAL - dist, 0.f);
            }
            #pragma unroll
            for (int off = 32; off; off >>= 1) acc += __shfl_down(acc, off, 64);
            if (lane == 0) redf[wave] = acc;
            __syncthreads();
            myPair = (float)mult * (redf[0] + redf[1] + redf[2] + redf[3]);
            if (e == 0) myCnt = mult * cnt;
        } else {
            if (e == 0) myCnt = 0;
        }
    }

    // ---- epilogue: atomic-only communication, no fences ----
    if (t == 0) {
        if (isReg) {
            atomicAdd(&accf[1], myPair);
        } else {
            atomicAdd(&accf[0], myPair);
            if (myCnt > 0) atomicAdd(&acci[0], myCnt);
        }
        asm volatile("s_waitcnt vmcnt(0)" ::: "memory");  // adds at coherent point
        int old = atomicAdd(&acci[1], 1);
        if (old == GRID_N - 1) {        // last arrival: all adds are globally done
            float P = atomicAdd(&accf[0], 0.f);   // RMW read: guaranteed fresh
            float A = atomicAdd(&accf[1], 0.f);
            int   S = atomicAdd(&acci[0], 0);
            out[0] = 0.5f * P / (256.0f * (float)S)
                   + ALPHA * (A * (1.0f / 16384.0f));
        }
    }
}

extern "C" void kernel_launch(void* const* d_in, const int* in_sizes, int n_in,
                              void* d_out, int out_size, void* d_ws, size_t ws_size,
                              hipStream_t stream) {
    const float* u   = (const float*)d_in[0];
    const int*   y   = (const int*)d_in[1];
    const int*   ind = (const int*)d_in[2];
    const float* U   = (const float*)d_in[3];
    const float* Y   = (const float*)d_in[4];
    float* out = (float*)d_out;

    float* accf = (float*)d_ws;                   // [2]
    int*   acci = (int*)((char*)d_ws + 8);        // [2]

    hipMemsetAsync(d_ws, 0, 16, stream);          // reset accumulators + counter
    dsh_fused_kernel<<<dim3(GRID_N), dim3(256), 0, stream>>>(
        u, y, ind, U, Y, accf, acci, out);
}

// Round 6
// 22.805 us; speedup vs baseline: 1.9676x; 1.8246x over previous
//
#include <hip/hip_runtime.h>

#define NTRAIN 200000
#define NB     256
#define BIT    64
#define MAXS   30
#define NCLS   100
#define ESPL   8            // entry-chunks per class
#define EPB    4            // pool entries per block
#define CHUNK  4096
#define PERT   16
#define NCLSB  (NCLS * ESPL)        // 800
#define MVAL   128.0f
#define ALPHA  0.01f

// Block j = (class c = j>>3, entry-chunk e = j&7): build the first-MAXS
// ascending pool for class c over the virtually-scattered bank, then pair
// loss of all 256 u-rows vs pool entries [4e, min(4e+4,cnt)), x multiplicity.
__global__ __launch_bounds__(256) void dsh_main_kernel(
    const float* __restrict__ u, const int* __restrict__ y,
    const int* __restrict__ ind, const float* __restrict__ U,
    const float* __restrict__ Y,
    float* __restrict__ partial, int* __restrict__ cntw)
{
    __shared__ int   addl[NB];      // bank indices whose Yeff flips to c
    __shared__ int   reml[NB];      // bank indices whose Yeff flips away from c
    __shared__ float up_l[EPB * BIT];
    __shared__ int   pool[MAXS];
    __shared__ int   povr[EPB];
    __shared__ int   wsA[4], wsB[4], wsC[4];
    __shared__ float redf[4];

    const int t    = threadIdx.x;
    const int j    = blockIdx.x;
    const int lane = t & 63;
    const int wave = t >> 6;

    const int c = j >> 3;
    const int e = j & 7;
    const float cf = (float)c;

    // ---- issue all front-end loads up front (one vmcnt wall) ----
    const int myi = ind[t];
    const int myy = y[t];
    const int s0  = t * PERT;
    float4 yv0, yv1, yv2, yv3;          // Y chunk 0, prefetched
    {
        const float4* yp = (const float4*)(Y + s0);
        yv0 = yp[0]; yv1 = yp[1]; yv2 = yp[2]; yv3 = yp[3];
    }
    const float ybank = Y[myi];         // dependent gather, overlaps yv loads

    // ---- ballots: multiplicity + scatter-correction lists ----
    const bool ismem = (myy == c);
    const bool fneg  = ismem && (ybank != cf);    // becomes class c
    const bool fpos  = (!ismem) && (ybank == cf); // stops being class c
    unsigned long long balm = __ballot(ismem);
    unsigned long long bala = __ballot(fneg);
    unsigned long long balr = __ballot(fpos);
    if (lane == 0) {
        wsA[wave] = (int)__popcll(balm);
        wsB[wave] = (int)__popcll(bala);
        wsC[wave] = (int)__popcll(balr);
    }
    __syncthreads();
    const int mult = wsA[0] + wsA[1] + wsA[2] + wsA[3];

    if (mult == 0) {                    // class absent from batch
        if (t == 0) { partial[j] = 0.f; if (e == 0) cntw[c] = 0; }
        return;
    }

    const int nadd = wsB[0] + wsB[1] + wsB[2] + wsB[3];
    const int nrem = wsC[0] + wsC[1] + wsC[2] + wsC[3];
    int pa = 0, pr = 0;
    #pragma unroll
    for (int w = 0; w < 4; ++w) if (w < wave) { pa += wsB[w]; pr += wsC[w]; }
    const unsigned long long lm = (1ull << lane) - 1ull;
    if (fneg) addl[pa + (int)__popcll(bala & lm)] = myi;
    if (fpos) reml[pr + (int)__popcll(balr & lm)] = myi;
    __syncthreads();                    // lists ready; wsA reusable

    // ---- scan chunk 0 (prefetched Y values) ----
    unsigned mbits = 0;
    if (yv0.x == cf) mbits |= 1u << 0;
    if (yv0.y == cf) mbits |= 1u << 1;
    if (yv0.z == cf) mbits |= 1u << 2;
    if (yv0.w == cf) mbits |= 1u << 3;
    if (yv1.x == cf) mbits |= 1u << 4;
    if (yv1.y == cf) mbits |= 1u << 5;
    if (yv1.z == cf) mbits |= 1u << 6;
    if (yv1.w == cf) mbits |= 1u << 7;
    if (yv2.x == cf) mbits |= 1u << 8;
    if (yv2.y == cf) mbits |= 1u << 9;
    if (yv2.z == cf) mbits |= 1u << 10;
    if (yv2.w == cf) mbits |= 1u << 11;
    if (yv3.x == cf) mbits |= 1u << 12;
    if (yv3.y == cf) mbits |= 1u << 13;
    if (yv3.z == cf) mbits |= 1u << 14;
    if (yv3.w == cf) mbits |= 1u << 15;
    for (int a2 = 0; a2 < nadd; ++a2) {
        unsigned rel = (unsigned)(addl[a2] - s0);
        if (rel < (unsigned)PERT) mbits |= 1u << rel;
    }
    for (int r2 = 0; r2 < nrem; ++r2) {
        unsigned rel = (unsigned)(reml[r2] - s0);
        if (rel < (unsigned)PERT) mbits &= ~(1u << rel);
    }
    const int mcnt = __popc(mbits);

    int x = mcnt;                       // ordered inclusive wave scan
    #pragma unroll
    for (int off = 1; off < 64; off <<= 1) {
        int v2 = __shfl_up(x, off, 64);
        if (lane >= off) x += v2;
    }
    if (lane == 63) wsA[wave] = x;
    if (t < EPB) povr[t] = -1;          // piggyback before the barrier
    __syncthreads();
    int r = x - mcnt;
    #pragma unroll
    for (int w = 0; w < 4; ++w) if (w < wave) r += wsA[w];
    #pragma unroll
    for (int k = 0; k < PERT; ++k) {
        if ((mbits >> k) & 1u) {
            if (r < MAXS) pool[r] = s0 + k;
            ++r;
        }
    }
    int count = wsA[0] + wsA[1] + wsA[2] + wsA[3];
    __syncthreads();                    // pool settled; wsA free

    // ---- cold continuation (~3-4% of classes) ----
    for (int base = CHUNK; base < NTRAIN && count < MAXS; base += CHUNK) {
        const int s = base + t * PERT;
        unsigned mb = 0;
        int mc = 0;
        if (s < NTRAIN) {               // NTRAIN % PERT == 0: full vectors
            const float4* yp = (const float4*)(Y + s);
            float4 a0 = yp[0], a1 = yp[1], a2v = yp[2], a3 = yp[3];
            if (a0.x == cf) mb |= 1u << 0;
            if (a0.y == cf) mb |= 1u << 1;
            if (a0.z == cf) mb |= 1u << 2;
            if (a0.w == cf) mb |= 1u << 3;
            if (a1.x == cf) mb |= 1u << 4;
            if (a1.y == cf) mb |= 1u << 5;
            if (a1.z == cf) mb |= 1u << 6;
            if (a1.w == cf) mb |= 1u << 7;
            if (a2v.x == cf) mb |= 1u << 8;
            if (a2v.y == cf) mb |= 1u << 9;
            if (a2v.z == cf) mb |= 1u << 10;
            if (a2v.w == cf) mb |= 1u << 11;
            if (a3.x == cf) mb |= 1u << 12;
            if (a3.y == cf) mb |= 1u << 13;
            if (a3.z == cf) mb |= 1u << 14;
            if (a3.w == cf) mb |= 1u << 15;
            for (int a2 = 0; a2 < nadd; ++a2) {
                unsigned rel = (unsigned)(addl[a2] - s);
                if (rel < (unsigned)PERT) mb |= 1u << rel;
            }
            for (int r2 = 0; r2 < nrem; ++r2) {
                unsigned rel = (unsigned)(reml[r2] - s);
                if (rel < (unsigned)PERT) mb &= ~(1u << rel);
            }
            mc = __popc(mb);
        }
        int xx = mc;
        #pragma unroll
        for (int off = 1; off < 64; off <<= 1) {
            int v2 = __shfl_up(xx, off, 64);
            if (lane >= off) xx += v2;
        }
        if (lane == 63) wsA[wave] = xx;
        __syncthreads();
        int rr = count + (xx - mc);
        #pragma unroll
        for (int w = 0; w < 4; ++w) if (w < wave) rr += wsA[w];
        #pragma unroll
        for (int k = 0; k < PERT; ++k) {
            if ((mb >> k) & 1u) {
                if (rr < MAXS) pool[rr] = s + k;
                ++rr;
            }
        }
        count += wsA[0] + wsA[1] + wsA[2] + wsA[3];
        __syncthreads();
    }
    const int cnt = (count < MAXS) ? count : MAXS;

    // ---- overrides among this block's pool entries ----
    const int p0 = e * EPB;
    const int pe = (p0 + EPB < cnt) ? p0 + EPB : cnt;
    for (int k2 = p0; k2 < pe; ++k2)
        if (myi == pool[k2]) povr[k2 - p0] = t;   // at most one t matches
    __syncthreads();

    // ---- prefetch my u-row (hides under the U pool gather) + gather ----
    float4 ur[16];
    {
        const float4* urp = (const float4*)(u + t * BIT);
        #pragma unroll
        for (int q2 = 0; q2 < 16; ++q2) ur[q2] = urp[q2];
    }
    {
        const int pp = t >> 6;
        const int d  = t & 63;
        float v = 0.f;
        if (p0 + pp < pe) {
            const int ov = povr[pp];
            v = (ov >= 0) ? u[ov * BIT + d] : U[pool[p0 + pp] * BIT + d];
        }
        up_l[t] = v;
    }
    __syncthreads();

    // ---- pair loss: thread t = batch row t vs entries [p0, pe) ----
    const bool same = (myy == c);
    const int npool = pe - p0;
    float acc = 0.f;
    for (int pp = 0; pp < npool; ++pp) {
        const float4* up = (const float4*)(up_l + pp * BIT);  // LDS broadcast
        float d0 = 0.f, d1 = 0.f, d2 = 0.f, d3 = 0.f;
        #pragma unroll
        for (int q2 = 0; q2 < 16; ++q2) {
            float4 v = up[q2];
            float a0 = ur[q2].x - v.x; d0 += a0 * a0;
            float a1 = ur[q2].y - v.y; d1 += a1 * a1;
            float a2 = ur[q2].z - v.z; d2 += a2 * a2;
            float a3 = ur[q2].w - v.w; d3 += a3 * a3;
        }
        const float dist = (d0 + d1) + (d2 + d3);
        acc += same ? dist : fmaxf(MVAL - dist, 0.f);
    }
    #pragma unroll
    for (int off = 32; off; off >>= 1) acc += __shfl_down(acc, off, 64);
    if (lane == 0) redf[wave] = acc;
    __syncthreads();
    if (t == 0) {
        partial[j] = (float)mult * (redf[0] + redf[1] + redf[2] + redf[3]);
        if (e == 0) cntw[c] = mult * cnt;
    }
}

// Final: regularizer (64 KB coalesced u reads) + reduce 800 partials + cntw.
__global__ __launch_bounds__(256) void dsh_final_kernel(
    const float* __restrict__ u,
    const float* __restrict__ partial, const int* __restrict__ cntw,
    float* __restrict__ out)
{
    const int t = threadIdx.x;
    const int lane = t & 63, wave = t >> 6;
    __shared__ float redp[4], reda[4];
    __shared__ int   redc[4];

    float p = partial[t] + partial[t + 256] + partial[t + 512];
    if (t < NCLSB - 768) p += partial[t + 768];
    int cc = (t < NCLS) ? cntw[t] : 0;

    float a = 0.f;
    #pragma unroll
    for (int k = 0; k < 16; ++k) {      // 16384 floats, float4-coalesced
        float4 v = ((const float4*)u)[t + 256 * k];
        a += fabsf(fabsf(v.x) - 1.f) + fabsf(fabsf(v.y) - 1.f)
           + fabsf(fabsf(v.z) - 1.f) + fabsf(fabsf(v.w) - 1.f);
    }
    #pragma unroll
    for (int off = 32; off; off >>= 1) {
        p  += __shfl_down(p,  off, 64);
        a  += __shfl_down(a,  off, 64);
        cc += __shfl_down(cc, off, 64);
    }
    if (lane == 0) { redp[wave] = p; reda[wave] = a; redc[wave] = cc; }
    __syncthreads();
    if (t == 0) {
        const float P = redp[0] + redp[1] + redp[2] + redp[3];
        const float A = reda[0] + reda[1] + reda[2] + reda[3];
        const int   S = redc[0] + redc[1] + redc[2] + redc[3];
        out[0] = 0.5f * P / (256.0f * (float)S)
               + ALPHA * (A * (1.0f / 16384.0f));
    }
}

extern "C" void kernel_launch(void* const* d_in, const int* in_sizes, int n_in,
                              void* d_out, int out_size, void* d_ws, size_t ws_size,
                              hipStream_t stream) {
    const float* u   = (const float*)d_in[0];
    const int*   y   = (const int*)d_in[1];
    const int*   ind = (const int*)d_in[2];
    const float* U   = (const float*)d_in[3];
    const float* Y   = (const float*)d_in[4];
    float* out = (float*)d_out;

    float* partial = (float*)d_ws;                    // [800]
    int*   cntw    = (int*)((char*)d_ws + 4096);      // [100]

    dsh_main_kernel<<<dim3(NCLSB), dim3(256), 0, stream>>>(
        u, y, ind, U, Y, partial, cntw);
    dsh_final_kernel<<<dim3(1), dim3(256), 0, stream>>>(u, partial, cntw, out);
}